// Round 8
// baseline (413.821 us; speedup 1.0000x reference)
//
#include <hip/hip_runtime.h>
#include <hip/hip_fp16.h>
#include <math.h>

// Fan-beam CT forward projection — analytic Siddon, dominant-axis interval
// merge (R13).
//
// Evolution: R10 dual-endpoint rank merge (404us) -> R12 padded table +
// fused prep (395us). R13 removes the per-segment rank search entirely:
// geom orients each ray so the X-AP has the SMALLER step (sx <= sy); then
// every interval (X[j-1], X[j]] contains at most one Y-crossing (step
// ratio >= 1), so lane j derives its <=2 segments from one seeded +-1
// count k = #{Y < X[j-1]}. A second Y can sneak in only via fp32 jitter
// at ~45-degree rays: covered by a third segment under __any() (never
// taken in practice). Segment endpoints are the same fmaf(k,step,base)
// values as R12 -> same partition. Y-dominant rays use a transposed
// padded table (PT2) so adjacent lanes stay contiguous in memory;
// table select is wave-uniform (one ray per wave).

constexpr int IMG_N  = 256;
constexpr int NDET   = 368;
constexpr int NVIEW  = 180;
constexpr int NSAMP  = 2 * IMG_N + 1;       // 513
constexpr int DV     = NDET * NVIEW;        // 66240
constexpr int NITER  = (NSAMP + 63) / 64;   // 9 (fallback kernel)
constexpr int PN     = IMG_N + 1;           // 257 (padded table dim)

struct __align__(8) Corner { __half2 ab; __half2 cd; };

// ws layout: P2 | PT2 | rt (3 float4/ray) | kr (int4/ray)
constexpr size_t PACK_BYTES = (size_t)PN * PN * sizeof(Corner);       // 528 KB
constexpr size_t PT_OFF     = (PACK_BYTES + 255) & ~(size_t)255;
constexpr size_t RT_OFF     = (PT_OFF + PACK_BYTES + 255) & ~(size_t)255;
constexpr size_t RT_BYTES   = (size_t)DV * 3 * sizeof(float4);        // 3.2 MB
constexpr size_t KR_OFF     = RT_OFF + RT_BYTES;
constexpr size_t KR_BYTES   = (size_t)DV * sizeof(int4);
constexpr size_t WS_NEEDED  = KR_OFF + KR_BYTES;                      // ~5.3 MB

constexpr int PACK_BLOCKS = (PN * PN + 255) / 256;                    // 259
constexpr int GEOM_BLOCKS = (DV + 255) / 256;                         // 259

__device__ __forceinline__ double valAP(double A, double s, double inv, int k) {
    return (A + s * (double)k) * inv;
}

// ---- fused prep: [0,259) P2 row-major | [259,518) PT2 transposed |
//      [518,777) per-ray geometry ----
__global__ __launch_bounds__(256) void prep_kernel(
    const float* __restrict__ img, Corner* __restrict__ P2,
    Corner* __restrict__ PT2, float4* __restrict__ rt, int4* __restrict__ kr)
{
    const int b = blockIdx.x;
    if (b < 2 * PACK_BLOCKS) {
        const bool tr = (b >= PACK_BLOCKS);
        const int idx = (tr ? b - PACK_BLOCKS : b) * 256 + threadIdx.x;
        if (idx >= PN * PN) return;
        const int oi = idx / PN;          // outer index
        const int ii = idx - oi * PN;     // inner index (contiguous)
        // normal: outer=y, inner=x ; transposed: outer=x, inner=y
        const int y0 = (tr ? ii : oi) - 1;
        const int x0 = (tr ? oi : ii) - 1;
        float v[2][2];                    // v[dy][dx]
        #pragma unroll
        for (int dy = 0; dy < 2; ++dy)
            #pragma unroll
            for (int dx = 0; dx < 2; ++dx) {
                const int y = y0 + dy, x = x0 + dx;
                v[dy][dx] = (((unsigned)y) < 256u && ((unsigned)x) < 256u)
                          ? img[y * IMG_N + x] : 0.0f;
            }
        Corner c;
        if (!tr) {   // ab=(v00,v01) inner=x varies in ab; cd=(v10,v11)
            c.ab = __floats2half2_rn(v[0][0], v[0][1]);
            c.cd = __floats2half2_rn(v[1][0], v[1][1]);
            P2[idx] = c;
        } else {     // inner=y varies in ab: ab=(v00,v10); cd=(v01,v11)
            c.ab = __floats2half2_rn(v[0][0], v[1][0]);
            c.cd = __floats2half2_rn(v[0][1], v[1][1]);
            PT2[idx] = c;
        }
        return;
    }

    const int idx = (b - 2 * PACK_BLOCKS) * 256 + threadIdx.x;
    if (idx >= DV) return;
    const int d = idx / NVIEW;
    const int v = idx - d * NVIEW;

    const double d_beta = ((M_PI * 360.0) / (double)NVIEW) / 180.0;
    const double stop   = (double)(NVIEW - 1) * d_beta;
    const double step   = stop / (double)(NVIEW - 1);
    const double beta   = (v == NVIEW - 1) ? stop : (double)v * step;
    const double cb = cos(beta), sb = sin(beta);

    const double sx  = -500.0 * cb;
    const double sy  =  500.0 * sb;
    const double rdy = ((double)d - 183.5) * 2.0;
    const double dx  = cb * 500.0 + sb * rdy;
    const double dy  = (-sb) * 500.0 + cb * rdy;
    const double ddx = dx - sx, ddy = dy - sy;

    double Ax, sxn;
    const double invx = 1.0 / ddx;
    if (invx >= 0.0) { Ax = -128.0 - sx; sxn = 1.0; }
    else             { Ax =  128.0 - sx; sxn = -1.0; }
    double Ay, syn;
    const double invy = 1.0 / ddy;
    if (invy >= 0.0) { Ay = -128.0 - sy; syn = 1.0; }
    else             { Ay =  128.0 - sy; syn = -1.0; }

    const double vx0 = valAP(Ax, sxn, invx, 0), vxN = valAP(Ax, sxn, invx, IMG_N);
    const double vy0 = valAP(Ay, syn, invy, 0), vyN = valAP(Ay, syn, invy, IMG_N);
    double a_min = fmax(vx0, vy0); if (a_min < 0.0) a_min = 0.0;
    double a_max = fmin(vxN, vyN); if (a_max > 1.0) a_max = 1.0;

    const double absdx = fabs(ddx), absdy = fabs(ddy);

    int klox, khix, kloy, khiy;
    {
        double kd = (a_min - vx0) * absdx;
        kd = fmin(fmax(kd, -1.0), 258.0);
        int k = (int)kd; k = max(0, min(k, 256));
        while (k > 0    && valAP(Ax, sxn, invx, k - 1) >= a_min) --k;
        while (k <= 256 && valAP(Ax, sxn, invx, k) < a_min)      ++k;
        klox = k;
        kd = (a_max - vx0) * absdx;
        kd = fmin(fmax(kd, -1.0), 258.0);
        k = (int)kd; k = max(0, min(k, 256));
        while (k > 0    && valAP(Ax, sxn, invx, k - 1) > a_max)  --k;
        while (k <= 256 && valAP(Ax, sxn, invx, k) <= a_max)     ++k;
        khix = k - 1;
        if (klox > khix) { klox = 0; khix = -1; }
    }
    {
        double kd = (a_min - vy0) * absdy;
        kd = fmin(fmax(kd, -1.0), 258.0);
        int k = (int)kd; k = max(0, min(k, 256));
        while (k > 0    && valAP(Ay, syn, invy, k - 1) >= a_min) --k;
        while (k <= 256 && valAP(Ay, syn, invy, k) < a_min)      ++k;
        kloy = k;
        kd = (a_max - vy0) * absdy;
        kd = fmin(fmax(kd, -1.0), 258.0);
        k = (int)kd; k = max(0, min(k, 256));
        while (k > 0    && valAP(Ay, syn, invy, k - 1) > a_max)  --k;
        while (k <= 256 && valAP(Ay, syn, invy, k) <= a_max)     ++k;
        khiy = k - 1;
        if (kloy > khiy) { kloy = 0; khiy = -1; }
    }

    int nx = khix - klox + 1;
    int ny = khiy - kloy + 1;
    const double s2d = sqrt(ddx * ddx + ddy * ddy);

    double sxd = sxn * invx, syd = syn * invy;                 // both > 0
    double bxd = (Ax + sxn * (double)klox) * invx;
    double byd = (Ay + syn * (double)kloy) * invy;

    // pixel-coord maps (a-param -> pixel): x and y axes
    double cxa = ddx * (128.0 / 127.5), cxb = sx * (128.0 / 127.5) + 127.5;
    double cya = ddy * (128.0 / 127.5), cyb = sy * (128.0 / 127.5) + 127.5;

    // orient: X = axis with the SMALLER a-step (more crossings) so each
    // X-interval holds at most one Y crossing.
    int fl = 0;
    if (sxd > syd) {
        double t;
        t = bxd; bxd = byd; byd = t;
        t = sxd; sxd = syd; syd = t;
        int ti = nx; nx = ny; ny = ti;
        t = cxa; cxa = cya; cya = t;
        t = cxb; cxb = cyb; cyb = t;
        fl = 1;
    }

    float4* o = rt + (size_t)idx * 3;
    o[0] = make_float4((float)bxd, (float)sxd, (float)byd, (float)syd);
    o[1] = make_float4((float)(1.0 / syd), 0.0f, (float)s2d, 0.0f);
    o[2] = make_float4((float)cxa, (float)cxb, (float)cya, (float)cyb);
    kr[idx] = make_int4(nx, ny, fl, 0);
}

// one segment: cur -> nxt (valid), bilinear at midpoint from padded table
__device__ __forceinline__ float seg(float cur, float nxt, bool valid,
                                     const float4 C, const float s2d,
                                     const Corner* __restrict__ T)
{
    nxt = valid ? nxt : cur;                 // keep math finite
    const float diff = nxt - cur;
    const float mid  = fmaf(diff, 0.5f, cur);
    const float wfv  = valid ? diff * s2d : 0.0f;
    const float ip   = fmaf(mid, C.x, C.y);  // inner pixel coord
    const float op   = fmaf(mid, C.z, C.w);  // outer pixel coord
    const float fi = floorf(ip), fo = floorf(op);
    const float wi1 = ip - fi,  wo1 = op - fo;
    const int i0 = (int)fi, o0 = (int)fo;    // in [-1,255] by the math
    unsigned pidx = (unsigned)(o0 * PN + i0 + (PN + 1));
    pidx = min(pidx, (unsigned)(PN * PN - 1));   // fault guard only
    const Corner pc = T[pidx];
    const float2 r0 = __half22float2(pc.ab);
    const float2 r1 = __half22float2(pc.cd);
    const float wi0 = 1.0f - wi1, wo0 = 1.0f - wo1;
    const float interp = (r0.x * wi0 + r0.y * wi1) * wo0
                       + (r1.x * wi0 + r1.y * wi1) * wo1;
    return wfv * interp;
}

// ---- main: one wave per ray, lane = X-interval index ----
__global__ __launch_bounds__(256) void fp_siddon(
    const Corner* __restrict__ P2,
    const Corner* __restrict__ PT2,
    const float4* __restrict__ rt,
    const int4*   __restrict__ kr,
    float*        __restrict__ out)
{
    const int wave = threadIdx.x >> 6;
    const int lane = threadIdx.x & 63;
    const int dv   = __builtin_amdgcn_readfirstlane(blockIdx.x * 4 + wave);

    const float4 A = rt[(size_t)dv * 3 + 0];   // bx, sx, by, sy  (sx <= sy)
    const float4 B = rt[(size_t)dv * 3 + 1];   // invsy, -, s2d, -
    const float4 C = rt[(size_t)dv * 3 + 2];   // inner map, outer map
    const int4 kk = kr[dv];
    const int nx = kk.x, ny = kk.y;
    const Corner* __restrict__ T = kk.z ? PT2 : P2;   // wave-uniform

    float acc = 0.0f;

    // lane c owns interval (X[c-1], X[c]]; c==0: (-inf, X[0]); c==nx: post.
    for (int base = 0; base <= nx; base += 64) {
        const int c = base + lane;
        const bool act = (c <= nx);
        const int cc = act ? c : nx;
        const bool leftEx  = act && (cc >= 1);
        const bool rightEx = (cc < nx);
        const float left  = fmaf((float)(cc - 1), A.y, A.x);
        const float right = fmaf((float)cc,       A.y, A.x);

        // k = #{Y < left} (exact; seed + <=1-2 fixup steps). c==0 -> 0.
        int k = 0;
        if (cc > 0) {
            k = (int)((left - A.z) * B.x) + 1;
            k = max(0, min(k, ny));
            while (k > 0  && fmaf((float)(k - 1), A.w, A.z) >= left) --k;
            while (k < ny && fmaf((float)k,       A.w, A.z) <  left) ++k;
        }
        const float yk  = fmaf((float)k, A.w, A.z);
        const bool yIn  = (k < ny) && (!rightEx || yk < right);
        const float yk1 = fmaf((float)(k + 1), A.w, A.z);
        const bool y2   = yIn && (k + 1 < ny) && (!rightEx || yk1 < right);

        const bool  e1Ex = yIn || rightEx;
        const float e1   = yIn ? yk : right;
        const bool  e2Ex = yIn && (y2 || rightEx);
        const float e2   = y2 ? yk1 : right;

        const bool vA = leftEx && e1Ex;
        const bool vB = act && e2Ex;
        const bool vC = act && y2 && rightEx;   // fp32-jitter corner case

        acc += seg(left, e1, vA, C, B.z, T);
        acc += seg(e1,   e2, vB, C, B.z, T);
        if (__any(vC))
            acc += seg(e2, right, vC, C, B.z, T);
    }

    #pragma unroll
    for (int off = 32; off > 0; off >>= 1)
        acc += __shfl_down(acc, off, 64);
    if (lane == 0)
        out[dv] = isnan(acc) ? 0.0f : acc;
}

// ---- fallback (ws too small): stream-reading kernel ----
__global__ __launch_bounds__(256) void fp_kernel_nopack(
    const float*  __restrict__ img,
    const float2* __restrict__ grid,
    const float*  __restrict__ wt,
    float*        __restrict__ out)
{
    const int wave = threadIdx.x >> 6;
    const int lane = threadIdx.x & 63;
    const int dv   = blockIdx.x * 4 + wave;
    const long base = (long)dv * NSAMP;

    float2 g[NITER];
    float  w[NITER];
    #pragma unroll
    for (int k = 0; k < NITER; ++k) {
        const int s = lane + k * 64;
        if (s < NSAMP) { g[k] = grid[base + s]; w[k] = wt[base + s]; }
        else           { g[k] = make_float2(0.0f, 0.0f); w[k] = 0.0f; }
    }
    float acc = 0.0f;
    #pragma unroll
    for (int k = 0; k < NITER; ++k) {
        const float ix = ((g[k].x + 1.0f) * 256.0f - 1.0f) * 0.5f;
        const float iy = ((g[k].y + 1.0f) * 256.0f - 1.0f) * 0.5f;
        const float fx0 = floorf(ix), fy0 = floorf(iy);
        const float wx1 = ix - fx0,  wy1 = iy - fy0;
        const int x0 = (int)fx0, y0 = (int)fy0;
        const int xc  = min(max(x0, 0), IMG_N - 2);
        const int yc0 = min(max(y0, 0), IMG_N - 1);
        const int yc1 = min(max(y0 + 1, 0), IMG_N - 1);
        const float2 p0 = *(const float2*)(img + yc0 * IMG_N + xc);
        const float2 p1 = *(const float2*)(img + yc1 * IMG_N + xc);
        const bool x0v = ((unsigned)x0) < 256u;
        const bool x1v = ((unsigned)(x0 + 1)) < 256u;
        const bool hiX = (x0 == IMG_N - 1);
        const bool loX = (x0 == -1);
        const float v00 = x0v ? (hiX ? p0.y : p0.x) : 0.0f;
        const float v01 = x1v ? (loX ? p0.x : p0.y) : 0.0f;
        const float v10 = x0v ? (hiX ? p1.y : p1.x) : 0.0f;
        const float v11 = x1v ? (loX ? p1.x : p1.y) : 0.0f;
        const float my0 = (((unsigned)y0) < 256u) ? 1.0f : 0.0f;
        const float my1 = (((unsigned)(y0 + 1)) < 256u) ? 1.0f : 0.0f;
        const float wx0 = 1.0f - wx1;
        const float wy0 = (1.0f - wy1) * my0;
        const float wy1m = wy1 * my1;
        acc += w[k] * ((v00 * wx0 + v01 * wx1) * wy0
                     + (v10 * wx0 + v11 * wx1) * wy1m);
    }
    #pragma unroll
    for (int off = 32; off > 0; off >>= 1)
        acc += __shfl_down(acc, off, 64);
    if (lane == 0) out[dv] = isnan(acc) ? 0.0f : acc;
}

extern "C" void kernel_launch(void* const* d_in, const int* in_sizes, int n_in,
                              void* d_out, int out_size, void* d_ws, size_t ws_size,
                              hipStream_t stream) {
    const float*  img  = (const float*)d_in[0];
    const float2* grid = (const float2*)d_in[1];
    const float*  wt   = (const float*)d_in[2];
    float*        out  = (float*)d_out;

    if (ws_size >= WS_NEEDED) {
        Corner* P2  = (Corner*)d_ws;
        Corner* PT2 = (Corner*)((char*)d_ws + PT_OFF);
        float4* rt  = (float4*)((char*)d_ws + RT_OFF);
        int4*   kr  = (int4*)  ((char*)d_ws + KR_OFF);
        prep_kernel<<<2 * PACK_BLOCKS + GEOM_BLOCKS, 256, 0, stream>>>(
            img, P2, PT2, rt, kr);
        fp_siddon<<<DV / 4, 256, 0, stream>>>(P2, PT2, rt, kr, out);
    } else {
        fp_kernel_nopack<<<DV / 4, 256, 0, stream>>>(img, grid, wt, out);
    }
}

// Round 9
// 389.382 us; speedup vs baseline: 1.0628x; 1.0628x over previous
//
#include <hip/hip_runtime.h>
#include <hip/hip_fp16.h>
#include <math.h>

// Fan-beam CT forward projection — analytic Siddon, rank-based merge,
// dual-rank top-3 extraction (R14).
//
// R13 (dominant-axis) post-mortem: -30% iterations but 2 gathers+2 interps
// per interval -> 1.4x gathers, +18us. REVERTED to R12 structure.
// R14: one canonical rank-split per TWO consecutive segments. Lane owns
// pairs p0=base+2*lane and p0+1; split m of the first t'=p0+3 elements
// gives top-3 = merged[p0..p0+2] via 6 fmaf + ~8 selects (2-AP merge
// tail). Rank-search cost amortized over 2 segments, iterations halved,
// gathers per segment unchanged (1). Endpoint values are the same
// fmaf(k,step,base) expressions as R12 -> bit-identical segments.

constexpr int IMG_N  = 256;
constexpr int NDET   = 368;
constexpr int NVIEW  = 180;
constexpr int NSAMP  = 2 * IMG_N + 1;       // 513
constexpr int DV     = NDET * NVIEW;        // 66240
constexpr int NITER  = (NSAMP + 63) / 64;   // 9 (fallback kernel)
constexpr int PN     = IMG_N + 1;           // 257 (padded table dim)

struct __align__(8) Corner { __half2 ab; __half2 cd; };  // (v00,v01),(v10,v11)

// ws layout: padded fp16 corner table | rt: 3 float4/ray | kr: int2/ray
constexpr size_t PACK_BYTES = (size_t)PN * PN * sizeof(Corner);       // 528 KB
constexpr size_t RT_OFF     = (PACK_BYTES + 255) & ~(size_t)255;
constexpr size_t RT_BYTES   = (size_t)DV * 3 * sizeof(float4);        // 3.2 MB
constexpr size_t KR_OFF     = RT_OFF + RT_BYTES;
constexpr size_t KR_BYTES   = (size_t)DV * sizeof(int2);
constexpr size_t WS_NEEDED  = KR_OFF + KR_BYTES;                      // ~4.3 MB

constexpr int PACK_BLOCKS = (PN * PN + 255) / 256;                    // 259
constexpr int GEOM_BLOCKS = (DV + 255) / 256;                         // 259

__device__ __forceinline__ double valAP(double A, double s, double inv, int k) {
    return (A + s * (double)k) * inv;
}

// ---- fused prep: blocks [0,259) build padded corner table,
//      blocks [259,518) compute per-ray geometry (verified R7 version) ----
__global__ __launch_bounds__(256) void prep_kernel(
    const float* __restrict__ img, Corner* __restrict__ P2,
    float4* __restrict__ rt, int2* __restrict__ kr)
{
    const int b = blockIdx.x;
    if (b < PACK_BLOCKS) {
        const int idx = b * 256 + threadIdx.x;
        if (idx >= PN * PN) return;
        const int yi = idx / PN;
        const int xi = idx - yi * PN;
        const int y0 = yi - 1, x0 = xi - 1;
        float v[2][2];
        #pragma unroll
        for (int dy = 0; dy < 2; ++dy)
            #pragma unroll
            for (int dx = 0; dx < 2; ++dx) {
                const int y = y0 + dy, x = x0 + dx;
                v[dy][dx] = (((unsigned)y) < 256u && ((unsigned)x) < 256u)
                          ? img[y * IMG_N + x] : 0.0f;
            }
        Corner c;
        c.ab = __floats2half2_rn(v[0][0], v[0][1]);
        c.cd = __floats2half2_rn(v[1][0], v[1][1]);
        P2[idx] = c;
        return;
    }

    const int idx = (b - PACK_BLOCKS) * 256 + threadIdx.x;
    if (idx >= DV) return;
    const int d = idx / NVIEW;
    const int v = idx - d * NVIEW;

    const double d_beta = ((M_PI * 360.0) / (double)NVIEW) / 180.0;
    const double stop   = (double)(NVIEW - 1) * d_beta;
    const double step   = stop / (double)(NVIEW - 1);
    const double beta   = (v == NVIEW - 1) ? stop : (double)v * step;
    const double cb = cos(beta), sb = sin(beta);

    const double sx  = -500.0 * cb;
    const double sy  =  500.0 * sb;
    const double rdy = ((double)d - 183.5) * 2.0;
    const double dx  = cb * 500.0 + sb * rdy;
    const double dy  = (-sb) * 500.0 + cb * rdy;
    const double ddx = dx - sx, ddy = dy - sy;

    double Ax, sxn;
    const double invx = 1.0 / ddx;
    if (invx >= 0.0) { Ax = -128.0 - sx; sxn = 1.0; }
    else             { Ax =  128.0 - sx; sxn = -1.0; }
    double Ay, syn;
    const double invy = 1.0 / ddy;
    if (invy >= 0.0) { Ay = -128.0 - sy; syn = 1.0; }
    else             { Ay =  128.0 - sy; syn = -1.0; }

    const double vx0 = valAP(Ax, sxn, invx, 0), vxN = valAP(Ax, sxn, invx, IMG_N);
    const double vy0 = valAP(Ay, syn, invy, 0), vyN = valAP(Ay, syn, invy, IMG_N);
    double a_min = fmax(vx0, vy0); if (a_min < 0.0) a_min = 0.0;
    double a_max = fmin(vxN, vyN); if (a_max > 1.0) a_max = 1.0;

    const double absdx = fabs(ddx), absdy = fabs(ddy);

    int klox, khix, kloy, khiy;
    {
        double kd = (a_min - vx0) * absdx;
        kd = fmin(fmax(kd, -1.0), 258.0);
        int k = (int)kd; k = max(0, min(k, 256));
        while (k > 0    && valAP(Ax, sxn, invx, k - 1) >= a_min) --k;
        while (k <= 256 && valAP(Ax, sxn, invx, k) < a_min)      ++k;
        klox = k;
        kd = (a_max - vx0) * absdx;
        kd = fmin(fmax(kd, -1.0), 258.0);
        k = (int)kd; k = max(0, min(k, 256));
        while (k > 0    && valAP(Ax, sxn, invx, k - 1) > a_max)  --k;
        while (k <= 256 && valAP(Ax, sxn, invx, k) <= a_max)     ++k;
        khix = k - 1;
        if (klox > khix) { klox = 0; khix = -1; }
    }
    {
        double kd = (a_min - vy0) * absdy;
        kd = fmin(fmax(kd, -1.0), 258.0);
        int k = (int)kd; k = max(0, min(k, 256));
        while (k > 0    && valAP(Ay, syn, invy, k - 1) >= a_min) --k;
        while (k <= 256 && valAP(Ay, syn, invy, k) < a_min)      ++k;
        kloy = k;
        kd = (a_max - vy0) * absdy;
        kd = fmin(fmax(kd, -1.0), 258.0);
        k = (int)kd; k = max(0, min(k, 256));
        while (k > 0    && valAP(Ay, syn, invy, k - 1) > a_max)  --k;
        while (k <= 256 && valAP(Ay, syn, invy, k) <= a_max)     ++k;
        khiy = k - 1;
        if (kloy > khiy) { kloy = 0; khiy = -1; }
    }

    const int nx = khix - klox + 1;
    const int ny = khiy - kloy + 1;
    const double s2d = sqrt(ddx * ddx + ddy * ddy);

    const double sxd = sxn * invx, syd = syn * invy;           // both > 0
    const double bxd = (Ax + sxn * (double)klox) * invx;
    const double byd = (Ay + syn * (double)kloy) * invy;
    const double ssum = sxd + syd;
    const double c0 = (byd - bxd) / ssum;
    const double c1 = syd / ssum;

    float4* o = rt + (size_t)idx * 3;
    o[0] = make_float4((float)bxd, (float)sxd, (float)byd, (float)syd);
    o[1] = make_float4((float)c0, (float)c1, (float)s2d, 0.0f);
    o[2] = make_float4((float)(ddx * (128.0 / 127.5)),
                       (float)(sx  * (128.0 / 127.5) + 127.5),
                       (float)(ddy * (128.0 / 127.5)),
                       (float)(sy  * (128.0 / 127.5) + 127.5));
    kr[idx] = make_int2(nx, ny);
}

// one segment: cur -> nxt (if valid), bilinear at midpoint, padded table
__device__ __forceinline__ float seg(float cur, float nxt, bool valid,
                                     const float4 C, const float s2d,
                                     const Corner* __restrict__ T)
{
    nxt = valid ? nxt : cur;                 // keep math finite
    const float diff = nxt - cur;
    const float mid  = fmaf(diff, 0.5f, cur);
    const float wfv  = valid ? diff * s2d : 0.0f;
    const float ip   = fmaf(mid, C.x, C.y);  // x pixel coord
    const float op   = fmaf(mid, C.z, C.w);  // y pixel coord
    const float fi = floorf(ip), fo = floorf(op);
    const float wi1 = ip - fi,  wo1 = op - fo;
    const int i0 = (int)fi, o0 = (int)fo;    // in [-1,255] by the math
    unsigned pidx = (unsigned)(o0 * PN + i0 + (PN + 1));
    pidx = min(pidx, (unsigned)(PN * PN - 1));   // fault guard only
    const Corner pc = T[pidx];
    const float2 r0 = __half22float2(pc.ab);
    const float2 r1 = __half22float2(pc.cd);
    const float wi0 = 1.0f - wi1, wo0 = 1.0f - wo1;
    const float interp = (r0.x * wi0 + r0.y * wi1) * wo0
                       + (r1.x * wi0 + r1.y * wi1) * wo1;
    return wfv * interp;
}

// ---- main: one wave per ray, lane = TWO consecutive pair indices ----
__global__ __launch_bounds__(256) void fp_siddon(
    const Corner* __restrict__ P2,
    const float4* __restrict__ rt,
    const int2*   __restrict__ kr,
    float*        __restrict__ out)
{
    const int wave = threadIdx.x >> 6;
    const int lane = threadIdx.x & 63;
    const int dv   = __builtin_amdgcn_readfirstlane(blockIdx.x * 4 + wave);

    const float4 A = rt[(size_t)dv * 3 + 0];   // bx, sx, by, sy
    const float4 B = rt[(size_t)dv * 3 + 1];   // c0, c1, s2d
    const float4 C = rt[(size_t)dv * 3 + 2];   // x map, y map
    const int2 nn = kr[dv];
    const int nx = nn.x, ny = nn.y;
    const int M = nx + ny;
    const int npairs = M - 1;

    float acc = 0.0f;

    for (int base = 0; base < npairs; base += 128) {
        const int p0 = base + (lane << 1);
        const bool act1 = (p0 < npairs);
        const bool act2 = (p0 + 1 < npairs);
        const int p  = act1 ? p0 : (npairs - 1);   // npairs >= 1 here
        const int tp = p + 2 + (act2 ? 1 : 0);     // elements considered

        // canonical split: smallest m in [mlo,mhi] with P(m);
        // P(m) = (no Y left) || (no X left) || Y[tp-1-m] <= X[m].
        const int mlo = max(0, tp - ny);
        const int mhi = min(nx, tp);
        int m = (int)fmaf((float)(tp - 1), B.y, B.x);
        m = max(mlo, min(m, mhi));
        while (m > mlo) {
            const int mm = m - 1;
            const bool Pmm = (tp - 1 - mm < 0) || (mm >= nx) ||
                (fmaf((float)(tp - 1 - mm), A.w, A.z) <= fmaf((float)mm, A.y, A.x));
            if (!Pmm) break;
            m = mm;
        }
        while (m < mhi) {
            const bool Pm = (tp - 1 - m < 0) || (m >= nx) ||
                (fmaf((float)(tp - 1 - m), A.w, A.z) <= fmaf((float)m, A.y, A.x));
            if (Pm) break;
            ++m;
        }

        // first tp elements = X[0..m) u Y[0..tp-m); extract top-3.
        const float xl  = (m > 0)      ? fmaf((float)(m - 1),      A.y, A.x) : -3.0e38f;
        const float xl2 = (m > 1)      ? fmaf((float)(m - 2),      A.y, A.x) : -3.0e38f;
        const float xl3 = (m > 2)      ? fmaf((float)(m - 3),      A.y, A.x) : -3.0e38f;
        const float yl  = (tp - m > 0) ? fmaf((float)(tp - 1 - m), A.w, A.z) : -3.0e38f;
        const float yl2 = (tp - m > 1) ? fmaf((float)(tp - 2 - m), A.w, A.z) : -3.0e38f;
        const float yl3 = (tp - m > 2) ? fmaf((float)(tp - 3 - m), A.w, A.z) : -3.0e38f;

        const bool xge = (xl >= yl);
        const float top1 = fmaxf(xl, yl);
        const float c2 = xge ? xl2 : xl;
        const float d2 = xge ? yl  : yl2;
        const bool x2ge = (c2 >= d2);
        const float top2 = fmaxf(c2, d2);
        const float xh3 = x2ge ? (xge ? xl3 : xl2) : (xge ? xl2 : xl);
        const float yh3 = x2ge ? (xge ? yl  : yl2) : (xge ? yl2 : yl3);
        const float top3 = fmaxf(xh3, yh3);

        // act2: merged[p..p+2] = (top3, top2, top1); else merged[p..p+1] =
        // (top2, top1). Segment A = (merged[p], merged[p+1]); B = next.
        const float sA0 = act2 ? top3 : top2;
        const float sA1 = act2 ? top2 : top1;
        acc += seg(sA0,  sA1,  act1, C, B.z, P2);
        acc += seg(top2, top1, act2, C, B.z, P2);
    }

    #pragma unroll
    for (int off = 32; off > 0; off >>= 1)
        acc += __shfl_down(acc, off, 64);
    if (lane == 0)
        out[dv] = isnan(acc) ? 0.0f : acc;
}

// ---- fallback (ws too small): stream-reading kernel ----
__global__ __launch_bounds__(256) void fp_kernel_nopack(
    const float*  __restrict__ img,
    const float2* __restrict__ grid,
    const float*  __restrict__ wt,
    float*        __restrict__ out)
{
    const int wave = threadIdx.x >> 6;
    const int lane = threadIdx.x & 63;
    const int dv   = blockIdx.x * 4 + wave;
    const long base = (long)dv * NSAMP;

    float2 g[NITER];
    float  w[NITER];
    #pragma unroll
    for (int k = 0; k < NITER; ++k) {
        const int s = lane + k * 64;
        if (s < NSAMP) { g[k] = grid[base + s]; w[k] = wt[base + s]; }
        else           { g[k] = make_float2(0.0f, 0.0f); w[k] = 0.0f; }
    }
    float acc = 0.0f;
    #pragma unroll
    for (int k = 0; k < NITER; ++k) {
        const float ix = ((g[k].x + 1.0f) * 256.0f - 1.0f) * 0.5f;
        const float iy = ((g[k].y + 1.0f) * 256.0f - 1.0f) * 0.5f;
        const float fx0 = floorf(ix), fy0 = floorf(iy);
        const float wx1 = ix - fx0,  wy1 = iy - fy0;
        const int x0 = (int)fx0, y0 = (int)fy0;
        const int xc  = min(max(x0, 0), IMG_N - 2);
        const int yc0 = min(max(y0, 0), IMG_N - 1);
        const int yc1 = min(max(y0 + 1, 0), IMG_N - 1);
        const float2 p0 = *(const float2*)(img + yc0 * IMG_N + xc);
        const float2 p1 = *(const float2*)(img + yc1 * IMG_N + xc);
        const bool x0v = ((unsigned)x0) < 256u;
        const bool x1v = ((unsigned)(x0 + 1)) < 256u;
        const bool hiX = (x0 == IMG_N - 1);
        const bool loX = (x0 == -1);
        const float v00 = x0v ? (hiX ? p0.y : p0.x) : 0.0f;
        const float v01 = x1v ? (loX ? p0.x : p0.y) : 0.0f;
        const float v10 = x0v ? (hiX ? p1.y : p1.x) : 0.0f;
        const float v11 = x1v ? (loX ? p1.x : p1.y) : 0.0f;
        const float my0 = (((unsigned)y0) < 256u) ? 1.0f : 0.0f;
        const float my1 = (((unsigned)(y0 + 1)) < 256u) ? 1.0f : 0.0f;
        const float wx0 = 1.0f - wx1;
        const float wy0 = (1.0f - wy1) * my0;
        const float wy1m = wy1 * my1;
        acc += w[k] * ((v00 * wx0 + v01 * wx1) * wy0
                     + (v10 * wx0 + v11 * wx1) * wy1m);
    }
    #pragma unroll
    for (int off = 32; off > 0; off >>= 1)
        acc += __shfl_down(acc, off, 64);
    if (lane == 0) out[dv] = isnan(acc) ? 0.0f : acc;
}

extern "C" void kernel_launch(void* const* d_in, const int* in_sizes, int n_in,
                              void* d_out, int out_size, void* d_ws, size_t ws_size,
                              hipStream_t stream) {
    const float*  img  = (const float*)d_in[0];
    const float2* grid = (const float2*)d_in[1];
    const float*  wt   = (const float*)d_in[2];
    float*        out  = (float*)d_out;

    if (ws_size >= WS_NEEDED) {
        Corner* P2 = (Corner*)d_ws;
        float4* rt = (float4*)((char*)d_ws + RT_OFF);
        int2*   kr = (int2*)  ((char*)d_ws + KR_OFF);
        prep_kernel<<<PACK_BLOCKS + GEOM_BLOCKS, 256, 0, stream>>>(img, P2, rt, kr);
        fp_siddon<<<DV / 4, 256, 0, stream>>>(P2, rt, kr, out);
    } else {
        fp_kernel_nopack<<<DV / 4, 256, 0, stream>>>(img, grid, wt, out);
    }
}

// Round 10
// 388.258 us; speedup vs baseline: 1.0658x; 1.0029x over previous
//
#include <hip/hip_runtime.h>
#include <hip/hip_fp16.h>
#include <math.h>

// Fan-beam CT forward projection — analytic Siddon, rank-based merge,
// quad-rank reverse-merge extraction (R15).
//
// Ladder: R10 dual-endpoint 404 -> R12 padded table 395 -> R14 dual-rank
// 389.4. R15: ONE canonical rank-split per FOUR consecutive segments.
// Lane anchors at tp = min(p0+5, M); split m of the first tp merged
// elements; a 5-step reverse merge walk (xi=m-1, yi=tp-1-m) yields
// merged[tp-5..tp-1] = e[0..4]; segments k: (e[k], e[k+1]) active iff
// pair index tp-5+k is in [p0, npairs). Search cost amortized 2x vs R14,
// iterations halved, gathers/segment unchanged (1). Tie-order in the
// walk is value-equivalent (equal values => identical value sequence).
// seg() now zeroes BOTH endpoints when invalid (kills all -3e38 -> inf
// -> NaN paths from partial windows at small M; R1/R6 lesson).
// Table index fused: pidx = (int)fmaf(fo,257,fi)+258 (exact < 2^24).

constexpr int IMG_N  = 256;
constexpr int NDET   = 368;
constexpr int NVIEW  = 180;
constexpr int NSAMP  = 2 * IMG_N + 1;       // 513
constexpr int DV     = NDET * NVIEW;        // 66240
constexpr int NITER  = (NSAMP + 63) / 64;   // 9 (fallback kernel)
constexpr int PN     = IMG_N + 1;           // 257 (padded table dim)

struct __align__(8) Corner { __half2 ab; __half2 cd; };  // (v00,v01),(v10,v11)

// ws layout: padded fp16 corner table | rt: 3 float4/ray | kr: int2/ray
constexpr size_t PACK_BYTES = (size_t)PN * PN * sizeof(Corner);       // 528 KB
constexpr size_t RT_OFF     = (PACK_BYTES + 255) & ~(size_t)255;
constexpr size_t RT_BYTES   = (size_t)DV * 3 * sizeof(float4);        // 3.2 MB
constexpr size_t KR_OFF     = RT_OFF + RT_BYTES;
constexpr size_t KR_BYTES   = (size_t)DV * sizeof(int2);
constexpr size_t WS_NEEDED  = KR_OFF + KR_BYTES;                      // ~4.3 MB

constexpr int PACK_BLOCKS = (PN * PN + 255) / 256;                    // 259
constexpr int GEOM_BLOCKS = (DV + 255) / 256;                         // 259

__device__ __forceinline__ double valAP(double A, double s, double inv, int k) {
    return (A + s * (double)k) * inv;
}

// ---- fused prep: blocks [0,259) build padded corner table,
//      blocks [259,518) compute per-ray geometry (verified R7 version) ----
__global__ __launch_bounds__(256) void prep_kernel(
    const float* __restrict__ img, Corner* __restrict__ P2,
    float4* __restrict__ rt, int2* __restrict__ kr)
{
    const int b = blockIdx.x;
    if (b < PACK_BLOCKS) {
        const int idx = b * 256 + threadIdx.x;
        if (idx >= PN * PN) return;
        const int yi = idx / PN;
        const int xi = idx - yi * PN;
        const int y0 = yi - 1, x0 = xi - 1;
        float v[2][2];
        #pragma unroll
        for (int dy = 0; dy < 2; ++dy)
            #pragma unroll
            for (int dx = 0; dx < 2; ++dx) {
                const int y = y0 + dy, x = x0 + dx;
                v[dy][dx] = (((unsigned)y) < 256u && ((unsigned)x) < 256u)
                          ? img[y * IMG_N + x] : 0.0f;
            }
        Corner c;
        c.ab = __floats2half2_rn(v[0][0], v[0][1]);
        c.cd = __floats2half2_rn(v[1][0], v[1][1]);
        P2[idx] = c;
        return;
    }

    const int idx = (b - PACK_BLOCKS) * 256 + threadIdx.x;
    if (idx >= DV) return;
    const int d = idx / NVIEW;
    const int v = idx - d * NVIEW;

    const double d_beta = ((M_PI * 360.0) / (double)NVIEW) / 180.0;
    const double stop   = (double)(NVIEW - 1) * d_beta;
    const double step   = stop / (double)(NVIEW - 1);
    const double beta   = (v == NVIEW - 1) ? stop : (double)v * step;
    const double cb = cos(beta), sb = sin(beta);

    const double sx  = -500.0 * cb;
    const double sy  =  500.0 * sb;
    const double rdy = ((double)d - 183.5) * 2.0;
    const double dx  = cb * 500.0 + sb * rdy;
    const double dy  = (-sb) * 500.0 + cb * rdy;
    const double ddx = dx - sx, ddy = dy - sy;

    double Ax, sxn;
    const double invx = 1.0 / ddx;
    if (invx >= 0.0) { Ax = -128.0 - sx; sxn = 1.0; }
    else             { Ax =  128.0 - sx; sxn = -1.0; }
    double Ay, syn;
    const double invy = 1.0 / ddy;
    if (invy >= 0.0) { Ay = -128.0 - sy; syn = 1.0; }
    else             { Ay =  128.0 - sy; syn = -1.0; }

    const double vx0 = valAP(Ax, sxn, invx, 0), vxN = valAP(Ax, sxn, invx, IMG_N);
    const double vy0 = valAP(Ay, syn, invy, 0), vyN = valAP(Ay, syn, invy, IMG_N);
    double a_min = fmax(vx0, vy0); if (a_min < 0.0) a_min = 0.0;
    double a_max = fmin(vxN, vyN); if (a_max > 1.0) a_max = 1.0;

    const double absdx = fabs(ddx), absdy = fabs(ddy);

    int klox, khix, kloy, khiy;
    {
        double kd = (a_min - vx0) * absdx;
        kd = fmin(fmax(kd, -1.0), 258.0);
        int k = (int)kd; k = max(0, min(k, 256));
        while (k > 0    && valAP(Ax, sxn, invx, k - 1) >= a_min) --k;
        while (k <= 256 && valAP(Ax, sxn, invx, k) < a_min)      ++k;
        klox = k;
        kd = (a_max - vx0) * absdx;
        kd = fmin(fmax(kd, -1.0), 258.0);
        k = (int)kd; k = max(0, min(k, 256));
        while (k > 0    && valAP(Ax, sxn, invx, k - 1) > a_max)  --k;
        while (k <= 256 && valAP(Ax, sxn, invx, k) <= a_max)     ++k;
        khix = k - 1;
        if (klox > khix) { klox = 0; khix = -1; }
    }
    {
        double kd = (a_min - vy0) * absdy;
        kd = fmin(fmax(kd, -1.0), 258.0);
        int k = (int)kd; k = max(0, min(k, 256));
        while (k > 0    && valAP(Ay, syn, invy, k - 1) >= a_min) --k;
        while (k <= 256 && valAP(Ay, syn, invy, k) < a_min)      ++k;
        kloy = k;
        kd = (a_max - vy0) * absdy;
        kd = fmin(fmax(kd, -1.0), 258.0);
        k = (int)kd; k = max(0, min(k, 256));
        while (k > 0    && valAP(Ay, syn, invy, k - 1) > a_max)  --k;
        while (k <= 256 && valAP(Ay, syn, invy, k) <= a_max)     ++k;
        khiy = k - 1;
        if (kloy > khiy) { kloy = 0; khiy = -1; }
    }

    const int nx = khix - klox + 1;
    const int ny = khiy - kloy + 1;
    const double s2d = sqrt(ddx * ddx + ddy * ddy);

    const double sxd = sxn * invx, syd = syn * invy;           // both > 0
    const double bxd = (Ax + sxn * (double)klox) * invx;
    const double byd = (Ay + syn * (double)kloy) * invy;
    const double ssum = sxd + syd;
    const double c0 = (byd - bxd) / ssum;
    const double c1 = syd / ssum;

    float4* o = rt + (size_t)idx * 3;
    o[0] = make_float4((float)bxd, (float)sxd, (float)byd, (float)syd);
    o[1] = make_float4((float)c0, (float)c1, (float)s2d, 0.0f);
    o[2] = make_float4((float)(ddx * (128.0 / 127.5)),
                       (float)(sx  * (128.0 / 127.5) + 127.5),
                       (float)(ddy * (128.0 / 127.5)),
                       (float)(sy  * (128.0 / 127.5) + 127.5));
    kr[idx] = make_int2(nx, ny);
}

// one segment: cur -> nxt (if valid), bilinear at midpoint, padded table.
// Invalid lanes: BOTH endpoints zeroed -> every intermediate finite and
// in-range, contribution exactly 0 (wfv = 0).
__device__ __forceinline__ float seg(float cur, float nxt, bool valid,
                                     const float4 C, const float s2d,
                                     const Corner* __restrict__ T)
{
    cur = valid ? cur : 0.0f;
    nxt = valid ? nxt : cur;
    const float diff = nxt - cur;
    const float mid  = fmaf(diff, 0.5f, cur);
    const float wfv  = valid ? diff * s2d : 0.0f;
    const float ip   = fmaf(mid, C.x, C.y);  // x pixel coord
    const float op   = fmaf(mid, C.z, C.w);  // y pixel coord
    const float fi = floorf(ip), fo = floorf(op);
    const float wi1 = ip - fi,  wo1 = op - fo;
    // pidx = (o0+1)*257 + (i0+1); fo*257+fi exact (<2^24), +258 folds pads
    const float fidx = fmaf(fo, 257.0f, fi);
    unsigned pidx = (unsigned)((int)fidx + 258);
    pidx = min(pidx, (unsigned)(PN * PN - 1));   // fault guard only
    const Corner pc = T[pidx];
    const float2 r0 = __half22float2(pc.ab);
    const float2 r1 = __half22float2(pc.cd);
    const float wi0 = 1.0f - wi1, wo0 = 1.0f - wo1;
    const float interp = (r0.x * wi0 + r0.y * wi1) * wo0
                       + (r1.x * wi0 + r1.y * wi1) * wo1;
    return wfv * interp;
}

// ---- main: one wave per ray, lane = FOUR consecutive pair indices ----
__global__ __launch_bounds__(256) void fp_siddon(
    const Corner* __restrict__ P2,
    const float4* __restrict__ rt,
    const int2*   __restrict__ kr,
    float*        __restrict__ out)
{
    const int wave = threadIdx.x >> 6;
    const int lane = threadIdx.x & 63;
    const int dv   = __builtin_amdgcn_readfirstlane(blockIdx.x * 4 + wave);

    const float4 A = rt[(size_t)dv * 3 + 0];   // bx, sx, by, sy
    const float4 B = rt[(size_t)dv * 3 + 1];   // c0, c1, s2d
    const float4 C = rt[(size_t)dv * 3 + 2];   // x map, y map
    const int2 nn = kr[dv];
    const int nx = nn.x, ny = nn.y;
    const int M = nx + ny;
    const int npairs = M - 1;

    float acc = 0.0f;

    for (int base = 0; base < npairs; base += 256) {
        const int p0 = base + (lane << 2);
        const int tp = min(p0 + 5, M);         // window end (M >= 2 here)

        // canonical split: smallest m in [mlo,mhi] with P(m);
        // P(m) = (no Y left) || (no X left) || Y[tp-1-m] <= X[m].
        const int mlo = max(0, tp - ny);
        const int mhi = min(nx, tp);
        int m = (int)fmaf((float)(tp - 1), B.y, B.x);
        m = max(mlo, min(m, mhi));
        while (m > mlo) {
            const int mm = m - 1;
            const bool Pmm = (tp - 1 - mm < 0) || (mm >= nx) ||
                (fmaf((float)(tp - 1 - mm), A.w, A.z) <= fmaf((float)mm, A.y, A.x));
            if (!Pmm) break;
            m = mm;
        }
        while (m < mhi) {
            const bool Pm = (tp - 1 - m < 0) || (m >= nx) ||
                (fmaf((float)(tp - 1 - m), A.w, A.z) <= fmaf((float)m, A.y, A.x));
            if (Pm) break;
            ++m;
        }

        // reverse merge walk: e[0..4] = merged[tp-5 .. tp-1]
        int xi = m - 1;                // largest X index among first tp
        int yi = tp - 1 - m;           // largest Y index among first tp
        float e0, e1, e2, e3, e4;
        {
            float xv, yv; bool tx;
            xv = (xi >= 0) ? fmaf((float)xi, A.y, A.x) : -3.0e38f;
            yv = (yi >= 0) ? fmaf((float)yi, A.w, A.z) : -3.0e38f;
            tx = (xv >= yv); e4 = tx ? xv : yv; xi -= tx; yi -= !tx;
            xv = (xi >= 0) ? fmaf((float)xi, A.y, A.x) : -3.0e38f;
            yv = (yi >= 0) ? fmaf((float)yi, A.w, A.z) : -3.0e38f;
            tx = (xv >= yv); e3 = tx ? xv : yv; xi -= tx; yi -= !tx;
            xv = (xi >= 0) ? fmaf((float)xi, A.y, A.x) : -3.0e38f;
            yv = (yi >= 0) ? fmaf((float)yi, A.w, A.z) : -3.0e38f;
            tx = (xv >= yv); e2 = tx ? xv : yv; xi -= tx; yi -= !tx;
            xv = (xi >= 0) ? fmaf((float)xi, A.y, A.x) : -3.0e38f;
            yv = (yi >= 0) ? fmaf((float)yi, A.w, A.z) : -3.0e38f;
            tx = (xv >= yv); e1 = tx ? xv : yv; xi -= tx; yi -= !tx;
            xv = (xi >= 0) ? fmaf((float)xi, A.y, A.x) : -3.0e38f;
            yv = (yi >= 0) ? fmaf((float)yi, A.w, A.z) : -3.0e38f;
            tx = (xv >= yv); e0 = tx ? xv : yv;
        }

        // segments k: pair index pik = tp-5+k, active iff in [p0, npairs)
        const int pik0 = tp - 5;
        const bool a0 = (pik0     >= p0) && (pik0     < npairs);
        const bool a1 = (pik0 + 1 >= p0) && (pik0 + 1 < npairs);
        const bool a2 = (pik0 + 2 >= p0) && (pik0 + 2 < npairs);
        const bool a3 = (pik0 + 3 >= p0) && (pik0 + 3 < npairs);
        acc += seg(e0, e1, a0, C, B.z, P2);
        acc += seg(e1, e2, a1, C, B.z, P2);
        acc += seg(e2, e3, a2, C, B.z, P2);
        acc += seg(e3, e4, a3, C, B.z, P2);
    }

    #pragma unroll
    for (int off = 32; off > 0; off >>= 1)
        acc += __shfl_down(acc, off, 64);
    if (lane == 0)
        out[dv] = isnan(acc) ? 0.0f : acc;
}

// ---- fallback (ws too small): stream-reading kernel ----
__global__ __launch_bounds__(256) void fp_kernel_nopack(
    const float*  __restrict__ img,
    const float2* __restrict__ grid,
    const float*  __restrict__ wt,
    float*        __restrict__ out)
{
    const int wave = threadIdx.x >> 6;
    const int lane = threadIdx.x & 63;
    const int dv   = blockIdx.x * 4 + wave;
    const long base = (long)dv * NSAMP;

    float2 g[NITER];
    float  w[NITER];
    #pragma unroll
    for (int k = 0; k < NITER; ++k) {
        const int s = lane + k * 64;
        if (s < NSAMP) { g[k] = grid[base + s]; w[k] = wt[base + s]; }
        else           { g[k] = make_float2(0.0f, 0.0f); w[k] = 0.0f; }
    }
    float acc = 0.0f;
    #pragma unroll
    for (int k = 0; k < NITER; ++k) {
        const float ix = ((g[k].x + 1.0f) * 256.0f - 1.0f) * 0.5f;
        const float iy = ((g[k].y + 1.0f) * 256.0f - 1.0f) * 0.5f;
        const float fx0 = floorf(ix), fy0 = floorf(iy);
        const float wx1 = ix - fx0,  wy1 = iy - fy0;
        const int x0 = (int)fx0, y0 = (int)fy0;
        const int xc  = min(max(x0, 0), IMG_N - 2);
        const int yc0 = min(max(y0, 0), IMG_N - 1);
        const int yc1 = min(max(y0 + 1, 0), IMG_N - 1);
        const float2 p0 = *(const float2*)(img + yc0 * IMG_N + xc);
        const float2 p1 = *(const float2*)(img + yc1 * IMG_N + xc);
        const bool x0v = ((unsigned)x0) < 256u;
        const bool x1v = ((unsigned)(x0 + 1)) < 256u;
        const bool hiX = (x0 == IMG_N - 1);
        const bool loX = (x0 == -1);
        const float v00 = x0v ? (hiX ? p0.y : p0.x) : 0.0f;
        const float v01 = x1v ? (loX ? p0.x : p0.y) : 0.0f;
        const float v10 = x0v ? (hiX ? p1.y : p1.x) : 0.0f;
        const float v11 = x1v ? (loX ? p1.x : p1.y) : 0.0f;
        const float my0 = (((unsigned)y0) < 256u) ? 1.0f : 0.0f;
        const float my1 = (((unsigned)(y0 + 1)) < 256u) ? 1.0f : 0.0f;
        const float wx0 = 1.0f - wx1;
        const float wy0 = (1.0f - wy1) * my0;
        const float wy1m = wy1 * my1;
        acc += w[k] * ((v00 * wx0 + v01 * wx1) * wy0
                     + (v10 * wx0 + v11 * wx1) * wy1m);
    }
    #pragma unroll
    for (int off = 32; off > 0; off >>= 1)
        acc += __shfl_down(acc, off, 64);
    if (lane == 0) out[dv] = isnan(acc) ? 0.0f : acc;
}

extern "C" void kernel_launch(void* const* d_in, const int* in_sizes, int n_in,
                              void* d_out, int out_size, void* d_ws, size_t ws_size,
                              hipStream_t stream) {
    const float*  img  = (const float*)d_in[0];
    const float2* grid = (const float2*)d_in[1];
    const float*  wt   = (const float*)d_in[2];
    float*        out  = (float*)d_out;

    if (ws_size >= WS_NEEDED) {
        Corner* P2 = (Corner*)d_ws;
        float4* rt = (float4*)((char*)d_ws + RT_OFF);
        int2*   kr = (int2*)  ((char*)d_ws + KR_OFF);
        prep_kernel<<<PACK_BLOCKS + GEOM_BLOCKS, 256, 0, stream>>>(img, P2, rt, kr);
        fp_siddon<<<DV / 4, 256, 0, stream>>>(P2, rt, kr, out);
    } else {
        fp_kernel_nopack<<<DV / 4, 256, 0, stream>>>(img, grid, wt, out);
    }
}